// Round 8
// baseline (729.146 us; speedup 1.0000x reference)
//
#include <hip/hip_runtime.h>
#include <math.h>

#define NZ 40
#define NY 256
#define NX 256
#define NUX 257                 // Nx+1
#define NYX (NY*NX)             // 65536
#define KU (NY*NUX)             // per-k stride of U
#define KV ((NY+1)*NX)          // per-k stride of V
#define NUT (NZ*KU)
#define NVT (NZ*KV)
#define NCT (NZ*NYX)
#define NWT ((NZ-1)*NYX)
#define NBLK (NUX*NZ)           // 10280 = 8*1285
#define NHALF (NUT+NVT+NWT+3*NCT+NWT)   // total fp16 diag elements (even)

typedef _Float16 h16;

__device__ __forceinline__ int ICc(int k,int j,int i){ return (k*NY+j)*NX+i; }
__device__ __forceinline__ int IU (int k,int j,int i){ return (k*NY+j)*NUX+i; }
__device__ __forceinline__ int IV (int k,int j,int i){ return (k*(NY+1)+j)*NX+i; }

// fast divide: v_rcp_f32 (trans pipe, ~1e-5 rel err).
__device__ __forceinline__ float fdiv(float a, float b){
  return a * __builtin_amdgcn_rcpf(b);
}
__device__ __forceinline__ float ldh(const h16* __restrict__ a, int idx){
  return (float)a[idx];
}

// ---------------- diagnostics: u,v,w,theta,alpha,p,Omega -> fp16 ----------------
// grid (257, NZ), block 256.  j=blockIdx.x, k=blockIdx.y, i=threadIdx.x
__global__ __launch_bounds__(256) void diag_all(
    const float* __restrict__ Us, const float* __restrict__ Vs, const float* __restrict__ Ws,
    const float* __restrict__ Ts, const float* __restrict__ Ms, const float* __restrict__ Ps,
    h16* __restrict__ ud, h16* __restrict__ vd, h16* __restrict__ wd,
    h16* __restrict__ thd, h16* __restrict__ ald, h16* __restrict__ pd,
    h16* __restrict__ Omd,
    const float* __restrict__ dzp, const float* __restrict__ PREFp,
    const float* __restrict__ Rdp, const float* __restrict__ gp)
{
  const int i = threadIdx.x;     // 0..255
  const int j = blockIdx.x;      // 0..256
  const int k = blockIdx.y;
  const float rdz = 1.f/(*dzp);
  const float PREF = *PREFp, Rd = *Rdp, g = *gp;
  const float invP = 1.f/PREF;

  const int jj  = j & 255;
  const int jm1 = (j+255) & 255;

  // v = V / bar_y(pad_y(Mu)) : all j in 0..256
  {
    float mjm = Ms[(k*NY+jm1)*NX+i];
    float mjj = Ms[(k*NY+jj )*NX+i];
    const int o = IV(k,j,i);
    vd[o] = (h16)fdiv(Vs[o], 0.5f*(mjm+mjj));
  }

  if (j < NY) {
    const int b = (k*NY+j)*NX;
    float mi  = Ms[b+i];
    float mim = Ms[b+((i+255)&255)];
    ud[IU(k,j,i)] = (h16)fdiv(Us[IU(k,j,i)], 0.5f*(mim+mi));
    if (i == 255) {   // u edge column i=256
      ud[IU(k,j,256)] = (h16)fdiv(Us[IU(k,j,256)], 0.5f*(Ms[b+255]+Ms[b+0]));
    }

    const int c = b + i;
    float mu   = mi;
    float phim = (k>0)    ? Ps[c-NYX] : 0.f;
    float phik = (k<NZ-1) ? Ps[c]     : 0.f;
    float al   = -((phik-phim)*rdz)*__builtin_amdgcn_rcpf(mu);
    float th   = fdiv(Ts[c], mu);
    pd[c]  = (h16)(PREF*powf(Rd*th*invP*__builtin_amdgcn_rcpf(al), 1.4f));
    ald[c] = (h16)al;
    thd[c] = (h16)th;
    if (k < NZ-1) {
      float mup  = Ms[c+NYX];
      float phip = (k+1<NZ-1) ? Ps[c+NYX] : 0.f;
      float alp  = -((phip-phik)*rdz)*__builtin_amdgcn_rcpf(mup);
      float muz  = 0.5f*(mu+mup);
      wd[c]  = (h16)fdiv(Ws[c], muz);
      Omd[c] = (h16)(-Ws[c]*g*__builtin_amdgcn_rcpf(muz*(0.5f*(al+alp))));
    }
  }
}

// ---------------- fused RHS + stage update, x2 thread coarsening ----------------
// 1D grid NBLK with XCD swizzle; block 128; thread t handles i = 2t, 2t+1.
__global__ __launch_bounds__(128,8) void rhs_update(
    const float* __restrict__ Us, const float* __restrict__ Vs,
    const float* __restrict__ Ms, const float* __restrict__ Ps,
    const h16* __restrict__ ud, const h16* __restrict__ vd, const h16* __restrict__ wd,
    const h16* __restrict__ thd, const h16* __restrict__ ald, const h16* __restrict__ pd,
    const h16* __restrict__ Omd,
    const float* __restrict__ Ub, const float* __restrict__ Vb, const float* __restrict__ Wb,
    const float* __restrict__ Tb, const float* __restrict__ Mb, const float* __restrict__ Pb,
    float* __restrict__ Uo, float* __restrict__ Vo, float* __restrict__ Wo,
    float* __restrict__ To, float* __restrict__ Mo, float* __restrict__ Po,
    const float* __restrict__ dxp, const float* __restrict__ dyp, const float* __restrict__ dzp,
    const float* __restrict__ dtp, const float* __restrict__ gp, float cmul)
{
  // bijective XCD swizzle: NBLK = 8 * 1285
  const int bid = blockIdx.x;
  const int nb  = (bid & 7)*(NBLK/8) + (bid >> 3);
  const int j   = nb / NZ;       // 0..256
  const int k   = nb - NZ*j;     // 0..NZ-1
  const int i0  = 2*threadIdx.x; // 0,2,..,254 (provably even)

  const float rdx = 1.f/(*dxp), rdy = 1.f/(*dyp), rdz = 1.f/(*dzp);
  const float g = *gp;
  const float c = (*dtp)*cmul;

  const int jj  = j & 255;
  const int jm1 = (j+255) & 255;
  const int jp1c= (j+1) & 255;   // (j+1) wrap on 256-grid (used in j<NY context)

  // ---- R_U value at u-grid index iu (iW/iE wrapped u-grid neighbors) ----
  auto ru_val = [&](int iu, int iW, int iE)->float {
    const int ii_  = iu & 255;
    const int iim1 = (iu+255) & 255;
    const int bU   = k*KU + j*NUX;

    float ui0 = ldh(ud,bU+iu), uim = ldh(ud,bU+iW), uip = ldh(ud,bU+iE);
    float Uim = Us[bU+iW], Ui0 = Us[bU+iu], Uip = Us[bU+iE];
    float t1 = -(0.25f*(Ui0+Uip)*(ui0+uip) - 0.25f*(Uim+Ui0)*(uim+ui0))*rdx;

    float Vx0 = 0.5f*(Vs[IV(k,j  ,iim1)] + Vs[IV(k,j  ,ii_)]);
    float uy0 = 0.5f*(ldh(ud,IU(k,jm1,iu)) + ui0);
    float Vx1 = 0.5f*(Vs[IV(k,j+1,iim1)] + Vs[IV(k,j+1,ii_)]);
    float uy1 = 0.5f*(ui0 + ldh(ud,IU(k,jp1c,iu)));
    float t2 = -(Vx1*uy1 - Vx0*uy0)*rdy;

    float Omx0 = (k==0)   ? 0.f : 0.5f*(ldh(Omd,ICc(k-1,j,iim1))+ldh(Omd,ICc(k-1,j,ii_)));
    float uz0  = (k==0)   ? 0.5f*ui0 : 0.5f*(ldh(ud,IU(k-1,j,iu))+ui0);
    float Omx1 = (k+1==NZ)? 0.f : 0.5f*(ldh(Omd,ICc(k,j,iim1))+ldh(Omd,ICc(k,j,ii_)));
    float uz1  = (k+1==NZ)? 0.5f*ui0 : 0.5f*(ui0+ldh(ud,IU(k+1,j,iu)));
    float t3 = -(Omx1*uz1 - Omx0*uz0)*rdz;

    float Mux = 0.5f*(Ms[ICc(k,j,iim1)]+Ms[ICc(k,j,ii_)]);
    float alx = 0.5f*(ldh(ald,ICc(k,j,iim1))+ldh(ald,ICc(k,j,ii_)));
    float pt1 = -Mux*alx*(ldh(pd,ICc(k,j,ii_))-ldh(pd,ICc(k,j,iim1)))*rdx;

    auto pzf = [&](int m, int x)->float {
      if (m==0)  return 0.5f*ldh(pd,ICc(0,j,x));
      if (m==NZ) return 0.5f*ldh(pd,ICc(NZ-1,j,x));
      return 0.5f*(ldh(pd,ICc(m-1,j,x))+ldh(pd,ICc(m,j,x)));
    };
    float A = (0.5f*(pzf(k+1,iim1)+pzf(k+1,ii_)) - 0.5f*(pzf(k,iim1)+pzf(k,ii_)))*rdz;
    auto Phzf = [&](int x)->float {
      if (k==0)    return 0.5f*Ps[ICc(0,j,x)];
      if (k==NZ-1) return 0.5f*Ps[ICc(NZ-2,j,x)];
      return 0.5f*(Ps[ICc(k-1,j,x)]+Ps[ICc(k,j,x)]);
    };
    float B = (Phzf(ii_)-Phzf(iim1))*rdx;
    return t1+t2+t3+pt1 + (-A*B);
  };

  #pragma unroll
  for (int ip = 0; ip < 2; ++ip) {
    const int i   = i0 + ip;       // 0..255
    const int im1 = (i+255) & 255;
    const int ip1 = (i+1) & 255;

    // ================= R_U : j<NY =================
    if (j < NY) {
      const int iW = i ? (i-1) : 256;
      float rU = ru_val(i, iW, i+1);
      const int o = IU(k,j,i);
      Uo[o] = Ub[o] + c*rU;
      if (i == 255) {   // U edge column i=256 (wrap: iW=255, iE=0)
        float rUe = ru_val(256, 255, 0);
        const int oe = IU(k,j,256);
        Uo[oe] = Ub[oe] + c*rUe;
      }
    }

    // ================= R_V : all j in 0..256 =================
    {
      const int jN = (j==0)   ? 256 : j-1;   // (j-1) mod 257 on V-grid
      const int jS = (j==256) ? 0   : j+1;
      float vj0 = ldh(vd,IV(k,j,i));
      float vjm = ldh(vd,IV(k,jN,i));
      float vjp = ldh(vd,IV(k,jS,i));
      float Vjm = Vs[IV(k,jN,i)], Vj0 = Vs[IV(k,j,i)], Vjp = Vs[IV(k,jS,i)];
      float t2 = -(0.25f*(Vj0+Vjp)*(vj0+vjp) - 0.25f*(Vjm+Vj0)*(vjm+vj0))*rdy;

      float Uy0 = 0.5f*(Us[IU(k,jm1,i  )] + Us[IU(k,jj,i  )]);
      float vx0 = 0.5f*(ldh(vd,IV(k,j,im1)) + vj0);
      float Uy1 = 0.5f*(Us[IU(k,jm1,i+1)] + Us[IU(k,jj,i+1)]);
      float vx1 = 0.5f*(vj0 + ldh(vd,IV(k,j,ip1)));
      float t1 = -(Uy1*vx1 - Uy0*vx0)*rdx;

      float Omy0 = (k==0)   ? 0.f : 0.5f*(ldh(Omd,ICc(k-1,jm1,i))+ldh(Omd,ICc(k-1,jj,i)));
      float vz0  = (k==0)   ? 0.5f*vj0 : 0.5f*(ldh(vd,IV(k-1,j,i))+vj0);
      float Omy1 = (k+1==NZ)? 0.f : 0.5f*(ldh(Omd,ICc(k,jm1,i))+ldh(Omd,ICc(k,jj,i)));
      float vz1  = (k+1==NZ)? 0.5f*vj0 : 0.5f*(vj0+ldh(vd,IV(k+1,j,i)));
      float t3 = -(Omy1*vz1 - Omy0*vz0)*rdz;

      float Muy = 0.5f*(Ms[ICc(k,jm1,i)]+Ms[ICc(k,jj,i)]);
      float aly = 0.5f*(ldh(ald,ICc(k,jm1,i))+ldh(ald,ICc(k,jj,i)));
      float pt1 = -Muy*aly*(ldh(pd,ICc(k,jj,i))-ldh(pd,ICc(k,jm1,i)))*rdy;

      auto pzfy = [&](int m, int y)->float {
        if (m==0)  return 0.5f*ldh(pd,ICc(0,y,i));
        if (m==NZ) return 0.5f*ldh(pd,ICc(NZ-1,y,i));
        return 0.5f*(ldh(pd,ICc(m-1,y,i))+ldh(pd,ICc(m,y,i)));
      };
      float A = (0.5f*(pzfy(k+1,jm1)+pzfy(k+1,jj)) - 0.5f*(pzfy(k,jm1)+pzfy(k,jj)))*rdz;
      auto Phzfy = [&](int y)->float {
        if (k==0)    return 0.5f*Ps[ICc(0,y,i)];
        if (k==NZ-1) return 0.5f*Ps[ICc(NZ-2,y,i)];
        return 0.5f*(Ps[ICc(k-1,y,i)]+Ps[ICc(k,y,i)]);
      };
      float B = (Phzfy(jj)-Phzfy(jm1))*rdy;
      float pt2 = -A*B;

      const int o = IV(k,j,i);
      Vo[o] = Vb[o] + c*(t1+t2+t3+pt1+pt2);
    }

    // ================= center fields : j<NY =================
    if (j < NY) {
      const int cc = ICc(k,j,i);

      // ---- R_Theta ----
      float th0 = ldh(thd,cc);
      float thx0 = 0.5f*(ldh(thd,ICc(k,j,im1))+th0);
      float thx1 = 0.5f*(th0+ldh(thd,ICc(k,j,ip1)));
      float s1 = -(Us[IU(k,j,i+1)]*thx1 - Us[IU(k,j,i)]*thx0)*rdx;
      float thy0 = 0.5f*(ldh(thd,ICc(k,jm1,i))+th0);
      float thy1 = 0.5f*(th0+ldh(thd,ICc(k,jp1c,i)));
      float s2 = -(Vs[IV(k,j+1,i)]*thy1 - Vs[IV(k,j,i)]*thy0)*rdy;
      float Om0 = (k==0)    ? 0.f : ldh(Omd,ICc(k-1,j,i));
      float Om1 = (k+1==NZ) ? 0.f : ldh(Omd,cc);
      float thz0 = (k==0)    ? 0.5f*th0 : 0.5f*(ldh(thd,ICc(k-1,j,i))+th0);
      float thz1 = (k+1==NZ) ? 0.5f*th0 : 0.5f*(th0+ldh(thd,ICc(k+1,j,i)));
      float s3 = -(Om1*thz1 - Om0*thz0)*rdz;
      To[cc] = Tb[cc] + c*(s1+s2+s3);

      // ---- R_Mu ----
      float rmu = -(Us[IU(k,j,i+1)]-Us[IU(k,j,i)])*rdx
                  -(Vs[IV(k,j+1,i)]-Vs[IV(k,j,i)])*rdy
                  -(Om1-Om0)*rdz;
      Mo[cc] = Mb[cc] + c*rmu;

      if (k < NZ-1) {
        float w0 = ldh(wd,cc);
        // ---- R_W ----
        float Uz0 = 0.5f*(Us[IU(k,j,i  )]+Us[IU(k+1,j,i  )]);
        float Uz1 = 0.5f*(Us[IU(k,j,i+1)]+Us[IU(k+1,j,i+1)]);
        float wx0 = 0.5f*(ldh(wd,ICc(k,j,im1))+w0);
        float wx1 = 0.5f*(w0+ldh(wd,ICc(k,j,ip1)));
        float q1 = -(Uz1*wx1 - Uz0*wx0)*rdx;
        float Vz0 = 0.5f*(Vs[IV(k,j  ,i)]+Vs[IV(k+1,j  ,i)]);
        float Vz1 = 0.5f*(Vs[IV(k,j+1,i)]+Vs[IV(k+1,j+1,i)]);
        float wy0 = 0.5f*(ldh(wd,ICc(k,jm1,i))+w0);
        float wy1 = 0.5f*(w0+ldh(wd,ICc(k,jp1c,i)));
        float q2 = -(Vz1*wy1 - Vz0*wy0)*rdy;
        float Omz0 = (k==0)      ? 0.5f*ldh(Omd,ICc(0,j,i))    : 0.5f*(ldh(Omd,ICc(k-1,j,i))+ldh(Omd,cc));
        float wz0  = (k==0)      ? 0.5f*w0 : 0.5f*(ldh(wd,ICc(k-1,j,i))+w0);
        float Omz1 = (k+1==NZ-1) ? 0.5f*ldh(Omd,ICc(NZ-2,j,i)) : 0.5f*(ldh(Omd,cc)+ldh(Omd,ICc(k+1,j,i)));
        float wz1  = (k+1==NZ-1) ? 0.5f*w0 : 0.5f*(w0+ldh(wd,ICc(k+1,j,i)));
        float q3 = -(Omz1*wz1 - Omz0*wz0)*rdz;
        float pw = g*((ldh(pd,ICc(k+1,j,i))-ldh(pd,cc))*rdz - 0.5f*(Ms[cc]+Ms[ICc(k+1,j,i)]));
        Wo[cc] = Wb[cc] + c*(q1+q2+q3+pw);

        // ---- R_Phi ----
        float ux0 = 0.5f*(ldh(ud,IU(k  ,j,i))+ldh(ud,IU(k  ,j,i+1)));
        float ux1 = 0.5f*(ldh(ud,IU(k+1,j,i))+ldh(ud,IU(k+1,j,i+1)));
        float uzx = 0.5f*(ux0+ux1);
        float dPhx = 0.5f*(Ps[ICc(k,j,ip1)]-Ps[ICc(k,j,im1)])*rdx;
        float vy0 = 0.5f*(ldh(vd,IV(k  ,j,i))+ldh(vd,IV(k  ,j+1,i)));
        float vy1 = 0.5f*(ldh(vd,IV(k+1,j,i))+ldh(vd,IV(k+1,j+1,i)));
        float vzy = 0.5f*(vy0+vy1);
        float dPhy = 0.5f*(Ps[ICc(k,jp1c,i)]-Ps[ICc(k,jm1,i)])*rdy;
        float Phz0 = (k==0)      ? 0.5f*Ps[ICc(0,j,i)]    : 0.5f*(Ps[ICc(k-1,j,i)]+Ps[cc]);
        float Phz1 = (k+1==NZ-1) ? 0.5f*Ps[ICc(NZ-2,j,i)] : 0.5f*(Ps[cc]+Ps[ICc(k+1,j,i)]);
        float p3 = -ldh(Omd,cc)*(Phz1-Phz0)*rdz;
        Po[cc] = Pb[cc] + c*(-uzx*dPhx - vzy*dPhy + p3 + g*w0);
      }
    }
  }
}

extern "C" void kernel_launch(void* const* d_in, const int* in_sizes, int n_in,
                              void* d_out, int out_size, void* d_ws, size_t ws_size,
                              hipStream_t stream)
{
  const float* U = (const float*)d_in[0];
  const float* V = (const float*)d_in[1];
  const float* W = (const float*)d_in[2];
  const float* T = (const float*)d_in[3];
  const float* M = (const float*)d_in[4];
  const float* P = (const float*)d_in[5];
  const float* dxp  = (const float*)d_in[12];
  const float* dyp  = (const float*)d_in[13];
  const float* dzp  = (const float*)d_in[14];
  const float* dtp  = (const float*)d_in[15];
  const float* PREFp= (const float*)d_in[16];
  const float* Rdp  = (const float*)d_in[17];
  const float* gp   = (const float*)d_in[18];

  h16* hw = (h16*)d_ws;
  h16* ud  = hw;         h16* vd  = ud +NUT;  h16* wd = vd +NVT;
  h16* thd = wd +NWT;    h16* ald = thd+NCT;  h16* pd = ald+NCT;
  h16* Omd = pd +NCT;
  float* S = (float*)(hw + NHALF);   // NHALF even -> 4B aligned
  float* SU=S; float* SV=SU+NUT; float* SW=SV+NVT; float* ST=SW+NWT; float* SM=ST+NCT; float* SP=SM+NCT;

  float* o = (float*)d_out;
  float* OU=o; float* OV=OU+NUT; float* OW=OV+NVT; float* OT=OW+NWT; float* OM=OT+NCT; float* OP=OM+NCT;

  dim3 dblk(256,1,1), dgrd(NUX, NZ, 1);
  dim3 rblk(128,1,1), rgrd(NBLK, 1, 1);

  auto stage = [&](const float* sU,const float* sV,const float* sW,
                   const float* sT,const float* sM,const float* sP,
                   float* oU,float* oV,float* oW,float* oT,float* oM,float* oP,
                   float cmul){
    hipLaunchKernelGGL(diag_all, dgrd, dblk, 0, stream,
                       sU,sV,sW,sT,sM,sP, ud,vd,wd,thd,ald,pd,Omd, dzp,PREFp,Rdp,gp);
    hipLaunchKernelGGL(rhs_update, rgrd, rblk, 0, stream,
                       sU,sV,sM,sP, ud,vd,wd,thd,ald,pd,Omd,
                       U,V,W,T,M,P, oU,oV,oW,oT,oM,oP,
                       dxp,dyp,dzp,dtp,gp, cmul);
  };

  stage(U,V,W,T,M,P,          OU,OV,OW,OT,OM,OP, 1.f/3.f);
  stage(OU,OV,OW,OT,OM,OP,    SU,SV,SW,ST,SM,SP, 0.5f   );
  stage(SU,SV,SW,ST,SM,SP,    OU,OV,OW,OT,OM,OP, 1.f    );
}

// Round 9
// 374.583 us; speedup vs baseline: 1.9466x; 1.9466x over previous
//
#include <hip/hip_runtime.h>
#include <math.h>

#define NZ 40
#define NY 256
#define NX 256
#define NUX 257                 // Nx+1
#define NYX (NY*NX)             // 65536
#define KU (NY*NUX)             // per-k stride of U
#define KV ((NY+1)*NX)          // per-k stride of V
#define NUT (NZ*KU)
#define NVT (NZ*KV)
#define NCT (NZ*NYX)
#define NWT ((NZ-1)*NYX)
#define NBLK3 (NUX*(NZ/2))      // 5140 blocks (j x k-pair)
#define NHALF (NUT+NVT+NWT+3*NCT+NWT)   // total fp16 diag elements (even)

typedef _Float16 h16;

__device__ __forceinline__ int ICc(int k,int j,int i){ return (k*NY+j)*NX+i; }
__device__ __forceinline__ int IU (int k,int j,int i){ return (k*NY+j)*NUX+i; }
__device__ __forceinline__ int IV (int k,int j,int i){ return (k*(NY+1)+j)*NX+i; }

// fast divide: v_rcp_f32 (trans pipe, ~1e-5 rel err).
__device__ __forceinline__ float fdiv(float a, float b){
  return a * __builtin_amdgcn_rcpf(b);
}
__device__ __forceinline__ float ldh(const h16* __restrict__ a, int idx){
  return (float)a[idx];
}

// ---------------- diagnostics: u,v,w,theta,alpha,p,Omega -> fp16 ----------------
// grid (257, NZ), block 256.  j=blockIdx.x, k=blockIdx.y, i=threadIdx.x
__global__ __launch_bounds__(256) void diag_all(
    const float* __restrict__ Us, const float* __restrict__ Vs, const float* __restrict__ Ws,
    const float* __restrict__ Ts, const float* __restrict__ Ms, const float* __restrict__ Ps,
    h16* __restrict__ ud, h16* __restrict__ vd, h16* __restrict__ wd,
    h16* __restrict__ thd, h16* __restrict__ ald, h16* __restrict__ pd,
    h16* __restrict__ Omd,
    const float* __restrict__ dzp, const float* __restrict__ PREFp,
    const float* __restrict__ Rdp, const float* __restrict__ gp)
{
  const int i = threadIdx.x;     // 0..255
  const int j = blockIdx.x;      // 0..256
  const int k = blockIdx.y;
  const float rdz = 1.f/(*dzp);
  const float PREF = *PREFp, Rd = *Rdp, g = *gp;
  const float invP = 1.f/PREF;

  const int jj  = j & 255;
  const int jm1 = (j+255) & 255;

  // v = V / bar_y(pad_y(Mu)) : all j in 0..256
  {
    float mjm = Ms[(k*NY+jm1)*NX+i];
    float mjj = Ms[(k*NY+jj )*NX+i];
    const int o = IV(k,j,i);
    vd[o] = (h16)fdiv(Vs[o], 0.5f*(mjm+mjj));
  }

  if (j < NY) {
    const int b = (k*NY+j)*NX;
    float mi  = Ms[b+i];
    float mim = Ms[b+((i+255)&255)];
    ud[IU(k,j,i)] = (h16)fdiv(Us[IU(k,j,i)], 0.5f*(mim+mi));
    if (i == 255) {   // u edge column i=256
      ud[IU(k,j,256)] = (h16)fdiv(Us[IU(k,j,256)], 0.5f*(Ms[b+255]+Ms[b+0]));
    }

    const int c = b + i;
    float mu   = mi;
    float phim = (k>0)    ? Ps[c-NYX] : 0.f;
    float phik = (k<NZ-1) ? Ps[c]     : 0.f;
    float al   = -((phik-phim)*rdz)*__builtin_amdgcn_rcpf(mu);
    float th   = fdiv(Ts[c], mu);
    pd[c]  = (h16)(PREF*powf(Rd*th*invP*__builtin_amdgcn_rcpf(al), 1.4f));
    ald[c] = (h16)al;
    thd[c] = (h16)th;
    if (k < NZ-1) {
      float mup  = Ms[c+NYX];
      float phip = (k+1<NZ-1) ? Ps[c+NYX] : 0.f;
      float alp  = -((phip-phik)*rdz)*__builtin_amdgcn_rcpf(mup);
      float muz  = 0.5f*(mu+mup);
      wd[c]  = (h16)fdiv(Ws[c], muz);
      Omd[c] = (h16)(-Ws[c]*g*__builtin_amdgcn_rcpf(muz*(0.5f*(al+alp))));
    }
  }
}

// ---------------- fused RHS + stage update, k-pair coarsening ----------------
// 1D grid NBLK3 (j x k-pair) with bijective XCD swizzle; block 256; i = tid.
__global__ __launch_bounds__(256,4) void rhs_update(
    const float* __restrict__ Us, const float* __restrict__ Vs,
    const float* __restrict__ Ms, const float* __restrict__ Ps,
    const h16* __restrict__ ud, const h16* __restrict__ vd, const h16* __restrict__ wd,
    const h16* __restrict__ thd, const h16* __restrict__ ald, const h16* __restrict__ pd,
    const h16* __restrict__ Omd,
    const float* __restrict__ Ub, const float* __restrict__ Vb, const float* __restrict__ Wb,
    const float* __restrict__ Tb, const float* __restrict__ Mb, const float* __restrict__ Pb,
    float* __restrict__ Uo, float* __restrict__ Vo, float* __restrict__ Wo,
    float* __restrict__ To, float* __restrict__ Mo, float* __restrict__ Po,
    const float* __restrict__ dxp, const float* __restrict__ dyp, const float* __restrict__ dzp,
    const float* __restrict__ dtp, const float* __restrict__ gp, float cmul)
{
  // bijective XCD swizzle: 5140 = 8*642 + 4  (m204 formula)
  const int bid = blockIdx.x;
  const int q = NBLK3/8, r = NBLK3%8;
  const int xcd = bid & 7, pos = bid >> 3;
  const int nb  = (xcd<r ? xcd*(q+1) : r*(q+1)+(xcd-r)*q) + pos;
  const int j   = nb / (NZ/2);     // 0..256
  const int kp  = nb - (NZ/2)*j;   // 0..19
  const int i   = threadIdx.x;     // 0..255

  const float rdx = 1.f/(*dxp), rdy = 1.f/(*dyp), rdz = 1.f/(*dzp);
  const float g = *gp;
  const float c = (*dtp)*cmul;

  const int jj  = j & 255;
  const int jm1 = (j+255) & 255;
  const int jp1c= (j+1) & 255;   // (j+1) wrap on 256-grid (used in j<NY context)
  const int im1 = (i+255) & 255;
  const int ip1 = (i+1) & 255;
  const int jN  = (j==0)   ? 256 : j-1;   // (j-1) mod 257 on V-grid
  const int jS  = (j==256) ? 0   : j+1;

  #pragma unroll
  for (int ko = 0; ko < 2; ++ko) {
    const int k = 2*kp + ko;

    // ---- R_U value at u-grid index iu (iW/iE wrapped u-grid neighbors) ----
    auto ru_val = [&](int iu, int iW, int iE)->float {
      const int ii_  = iu & 255;
      const int iim1 = (iu+255) & 255;
      const int bU   = k*KU + j*NUX;

      float ui0 = ldh(ud,bU+iu), uim = ldh(ud,bU+iW), uip = ldh(ud,bU+iE);
      float Uim = Us[bU+iW], Ui0 = Us[bU+iu], Uip = Us[bU+iE];
      float t1 = -(0.25f*(Ui0+Uip)*(ui0+uip) - 0.25f*(Uim+Ui0)*(uim+ui0))*rdx;

      float Vx0 = 0.5f*(Vs[IV(k,j  ,iim1)] + Vs[IV(k,j  ,ii_)]);
      float uy0 = 0.5f*(ldh(ud,IU(k,jm1,iu)) + ui0);
      float Vx1 = 0.5f*(Vs[IV(k,j+1,iim1)] + Vs[IV(k,j+1,ii_)]);
      float uy1 = 0.5f*(ui0 + ldh(ud,IU(k,jp1c,iu)));
      float t2 = -(Vx1*uy1 - Vx0*uy0)*rdy;

      float Omx0 = (k==0)   ? 0.f : 0.5f*(ldh(Omd,ICc(k-1,j,iim1))+ldh(Omd,ICc(k-1,j,ii_)));
      float uz0  = (k==0)   ? 0.5f*ui0 : 0.5f*(ldh(ud,IU(k-1,j,iu))+ui0);
      float Omx1 = (k+1==NZ)? 0.f : 0.5f*(ldh(Omd,ICc(k,j,iim1))+ldh(Omd,ICc(k,j,ii_)));
      float uz1  = (k+1==NZ)? 0.5f*ui0 : 0.5f*(ui0+ldh(ud,IU(k+1,j,iu)));
      float t3 = -(Omx1*uz1 - Omx0*uz0)*rdz;

      float Mux = 0.5f*(Ms[ICc(k,j,iim1)]+Ms[ICc(k,j,ii_)]);
      float alx = 0.5f*(ldh(ald,ICc(k,j,iim1))+ldh(ald,ICc(k,j,ii_)));
      float pt1 = -Mux*alx*(ldh(pd,ICc(k,j,ii_))-ldh(pd,ICc(k,j,iim1)))*rdx;

      auto pzf = [&](int m, int x)->float {
        if (m==0)  return 0.5f*ldh(pd,ICc(0,j,x));
        if (m==NZ) return 0.5f*ldh(pd,ICc(NZ-1,j,x));
        return 0.5f*(ldh(pd,ICc(m-1,j,x))+ldh(pd,ICc(m,j,x)));
      };
      float A = (0.5f*(pzf(k+1,iim1)+pzf(k+1,ii_)) - 0.5f*(pzf(k,iim1)+pzf(k,ii_)))*rdz;
      auto Phzf = [&](int x)->float {
        if (k==0)    return 0.5f*Ps[ICc(0,j,x)];
        if (k==NZ-1) return 0.5f*Ps[ICc(NZ-2,j,x)];
        return 0.5f*(Ps[ICc(k-1,j,x)]+Ps[ICc(k,j,x)]);
      };
      float B = (Phzf(ii_)-Phzf(iim1))*rdx;
      return t1+t2+t3+pt1 + (-A*B);
    };

    // ================= R_U : j<NY =================
    if (j < NY) {
      const int iW = i ? (i-1) : 256;
      float rU = ru_val(i, iW, i+1);
      const int o = IU(k,j,i);
      Uo[o] = Ub[o] + c*rU;
      if (i == 255) {   // U edge column i=256 (wrap: iW=255, iE=0)
        float rUe = ru_val(256, 255, 0);
        const int oe = IU(k,j,256);
        Uo[oe] = Ub[oe] + c*rUe;
      }
    }

    // ================= R_V : all j in 0..256 =================
    {
      float vj0 = ldh(vd,IV(k,j,i));
      float vjm = ldh(vd,IV(k,jN,i));
      float vjp = ldh(vd,IV(k,jS,i));
      float Vjm = Vs[IV(k,jN,i)], Vj0 = Vs[IV(k,j,i)], Vjp = Vs[IV(k,jS,i)];
      float t2 = -(0.25f*(Vj0+Vjp)*(vj0+vjp) - 0.25f*(Vjm+Vj0)*(vjm+vj0))*rdy;

      float Uy0 = 0.5f*(Us[IU(k,jm1,i  )] + Us[IU(k,jj,i  )]);
      float vx0 = 0.5f*(ldh(vd,IV(k,j,im1)) + vj0);
      float Uy1 = 0.5f*(Us[IU(k,jm1,i+1)] + Us[IU(k,jj,i+1)]);
      float vx1 = 0.5f*(vj0 + ldh(vd,IV(k,j,ip1)));
      float t1 = -(Uy1*vx1 - Uy0*vx0)*rdx;

      float Omy0 = (k==0)   ? 0.f : 0.5f*(ldh(Omd,ICc(k-1,jm1,i))+ldh(Omd,ICc(k-1,jj,i)));
      float vz0  = (k==0)   ? 0.5f*vj0 : 0.5f*(ldh(vd,IV(k-1,j,i))+vj0);
      float Omy1 = (k+1==NZ)? 0.f : 0.5f*(ldh(Omd,ICc(k,jm1,i))+ldh(Omd,ICc(k,jj,i)));
      float vz1  = (k+1==NZ)? 0.5f*vj0 : 0.5f*(vj0+ldh(vd,IV(k+1,j,i)));
      float t3 = -(Omy1*vz1 - Omy0*vz0)*rdz;

      float Muy = 0.5f*(Ms[ICc(k,jm1,i)]+Ms[ICc(k,jj,i)]);
      float aly = 0.5f*(ldh(ald,ICc(k,jm1,i))+ldh(ald,ICc(k,jj,i)));
      float pt1 = -Muy*aly*(ldh(pd,ICc(k,jj,i))-ldh(pd,ICc(k,jm1,i)))*rdy;

      auto pzfy = [&](int m, int y)->float {
        if (m==0)  return 0.5f*ldh(pd,ICc(0,y,i));
        if (m==NZ) return 0.5f*ldh(pd,ICc(NZ-1,y,i));
        return 0.5f*(ldh(pd,ICc(m-1,y,i))+ldh(pd,ICc(m,y,i)));
      };
      float A = (0.5f*(pzfy(k+1,jm1)+pzfy(k+1,jj)) - 0.5f*(pzfy(k,jm1)+pzfy(k,jj)))*rdz;
      auto Phzfy = [&](int y)->float {
        if (k==0)    return 0.5f*Ps[ICc(0,y,i)];
        if (k==NZ-1) return 0.5f*Ps[ICc(NZ-2,y,i)];
        return 0.5f*(Ps[ICc(k-1,y,i)]+Ps[ICc(k,y,i)]);
      };
      float B = (Phzfy(jj)-Phzfy(jm1))*rdy;
      float pt2 = -A*B;

      const int o = IV(k,j,i);
      Vo[o] = Vb[o] + c*(t1+t2+t3+pt1+pt2);
    }

    // ================= center fields : j<NY =================
    if (j < NY) {
      const int cc = ICc(k,j,i);

      // ---- R_Theta ----
      float th0 = ldh(thd,cc);
      float thx0 = 0.5f*(ldh(thd,ICc(k,j,im1))+th0);
      float thx1 = 0.5f*(th0+ldh(thd,ICc(k,j,ip1)));
      float s1 = -(Us[IU(k,j,i+1)]*thx1 - Us[IU(k,j,i)]*thx0)*rdx;
      float thy0 = 0.5f*(ldh(thd,ICc(k,jm1,i))+th0);
      float thy1 = 0.5f*(th0+ldh(thd,ICc(k,jp1c,i)));
      float s2 = -(Vs[IV(k,j+1,i)]*thy1 - Vs[IV(k,j,i)]*thy0)*rdy;
      float Om0 = (k==0)    ? 0.f : ldh(Omd,ICc(k-1,j,i));
      float Om1 = (k+1==NZ) ? 0.f : ldh(Omd,cc);
      float thz0 = (k==0)    ? 0.5f*th0 : 0.5f*(ldh(thd,ICc(k-1,j,i))+th0);
      float thz1 = (k+1==NZ) ? 0.5f*th0 : 0.5f*(th0+ldh(thd,ICc(k+1,j,i)));
      float s3 = -(Om1*thz1 - Om0*thz0)*rdz;
      To[cc] = Tb[cc] + c*(s1+s2+s3);

      // ---- R_Mu ----
      float rmu = -(Us[IU(k,j,i+1)]-Us[IU(k,j,i)])*rdx
                  -(Vs[IV(k,j+1,i)]-Vs[IV(k,j,i)])*rdy
                  -(Om1-Om0)*rdz;
      Mo[cc] = Mb[cc] + c*rmu;

      if (k < NZ-1) {
        float w0 = ldh(wd,cc);
        // ---- R_W ----
        float Uz0 = 0.5f*(Us[IU(k,j,i  )]+Us[IU(k+1,j,i  )]);
        float Uz1 = 0.5f*(Us[IU(k,j,i+1)]+Us[IU(k+1,j,i+1)]);
        float wx0 = 0.5f*(ldh(wd,ICc(k,j,im1))+w0);
        float wx1 = 0.5f*(w0+ldh(wd,ICc(k,j,ip1)));
        float q1 = -(Uz1*wx1 - Uz0*wx0)*rdx;
        float Vz0 = 0.5f*(Vs[IV(k,j  ,i)]+Vs[IV(k+1,j  ,i)]);
        float Vz1 = 0.5f*(Vs[IV(k,j+1,i)]+Vs[IV(k+1,j+1,i)]);
        float wy0 = 0.5f*(ldh(wd,ICc(k,jm1,i))+w0);
        float wy1 = 0.5f*(w0+ldh(wd,ICc(k,jp1c,i)));
        float q2 = -(Vz1*wy1 - Vz0*wy0)*rdy;
        float Omz0 = (k==0)      ? 0.5f*ldh(Omd,ICc(0,j,i))    : 0.5f*(ldh(Omd,ICc(k-1,j,i))+ldh(Omd,cc));
        float wz0  = (k==0)      ? 0.5f*w0 : 0.5f*(ldh(wd,ICc(k-1,j,i))+w0);
        float Omz1 = (k+1==NZ-1) ? 0.5f*ldh(Omd,ICc(NZ-2,j,i)) : 0.5f*(ldh(Omd,cc)+ldh(Omd,ICc(k+1,j,i)));
        float wz1  = (k+1==NZ-1) ? 0.5f*w0 : 0.5f*(w0+ldh(wd,ICc(k+1,j,i)));
        float q3 = -(Omz1*wz1 - Omz0*wz0)*rdz;
        float pw = g*((ldh(pd,ICc(k+1,j,i))-ldh(pd,cc))*rdz - 0.5f*(Ms[cc]+Ms[ICc(k+1,j,i)]));
        Wo[cc] = Wb[cc] + c*(q1+q2+q3+pw);

        // ---- R_Phi ----
        float ux0 = 0.5f*(ldh(ud,IU(k  ,j,i))+ldh(ud,IU(k  ,j,i+1)));
        float ux1 = 0.5f*(ldh(ud,IU(k+1,j,i))+ldh(ud,IU(k+1,j,i+1)));
        float uzx = 0.5f*(ux0+ux1);
        float dPhx = 0.5f*(Ps[ICc(k,j,ip1)]-Ps[ICc(k,j,im1)])*rdx;
        float vy0 = 0.5f*(ldh(vd,IV(k  ,j,i))+ldh(vd,IV(k  ,j+1,i)));
        float vy1 = 0.5f*(ldh(vd,IV(k+1,j,i))+ldh(vd,IV(k+1,j+1,i)));
        float vzy = 0.5f*(vy0+vy1);
        float dPhy = 0.5f*(Ps[ICc(k,jp1c,i)]-Ps[ICc(k,jm1,i)])*rdy;
        float Phz0 = (k==0)      ? 0.5f*Ps[ICc(0,j,i)]    : 0.5f*(Ps[ICc(k-1,j,i)]+Ps[cc]);
        float Phz1 = (k+1==NZ-1) ? 0.5f*Ps[ICc(NZ-2,j,i)] : 0.5f*(Ps[cc]+Ps[ICc(k+1,j,i)]);
        float p3 = -ldh(Omd,cc)*(Phz1-Phz0)*rdz;
        Po[cc] = Pb[cc] + c*(-uzx*dPhx - vzy*dPhy + p3 + g*w0);
      }
    }
  }
}

extern "C" void kernel_launch(void* const* d_in, const int* in_sizes, int n_in,
                              void* d_out, int out_size, void* d_ws, size_t ws_size,
                              hipStream_t stream)
{
  const float* U = (const float*)d_in[0];
  const float* V = (const float*)d_in[1];
  const float* W = (const float*)d_in[2];
  const float* T = (const float*)d_in[3];
  const float* M = (const float*)d_in[4];
  const float* P = (const float*)d_in[5];
  const float* dxp  = (const float*)d_in[12];
  const float* dyp  = (const float*)d_in[13];
  const float* dzp  = (const float*)d_in[14];
  const float* dtp  = (const float*)d_in[15];
  const float* PREFp= (const float*)d_in[16];
  const float* Rdp  = (const float*)d_in[17];
  const float* gp   = (const float*)d_in[18];

  h16* hw = (h16*)d_ws;
  h16* ud  = hw;         h16* vd  = ud +NUT;  h16* wd = vd +NVT;
  h16* thd = wd +NWT;    h16* ald = thd+NCT;  h16* pd = ald+NCT;
  h16* Omd = pd +NCT;
  float* S = (float*)(hw + NHALF);   // NHALF even -> 4B aligned
  float* SU=S; float* SV=SU+NUT; float* SW=SV+NVT; float* ST=SW+NWT; float* SM=ST+NCT; float* SP=SM+NCT;

  float* o = (float*)d_out;
  float* OU=o; float* OV=OU+NUT; float* OW=OV+NVT; float* OT=OW+NWT; float* OM=OT+NCT; float* OP=OM+NCT;

  dim3 dblk(256,1,1), dgrd(NUX, NZ, 1);
  dim3 rblk(256,1,1), rgrd(NBLK3, 1, 1);

  auto stage = [&](const float* sU,const float* sV,const float* sW,
                   const float* sT,const float* sM,const float* sP,
                   float* oU,float* oV,float* oW,float* oT,float* oM,float* oP,
                   float cmul){
    hipLaunchKernelGGL(diag_all, dgrd, dblk, 0, stream,
                       sU,sV,sW,sT,sM,sP, ud,vd,wd,thd,ald,pd,Omd, dzp,PREFp,Rdp,gp);
    hipLaunchKernelGGL(rhs_update, rgrd, rblk, 0, stream,
                       sU,sV,sM,sP, ud,vd,wd,thd,ald,pd,Omd,
                       U,V,W,T,M,P, oU,oV,oW,oT,oM,oP,
                       dxp,dyp,dzp,dtp,gp, cmul);
  };

  stage(U,V,W,T,M,P,          OU,OV,OW,OT,OM,OP, 1.f/3.f);
  stage(OU,OV,OW,OT,OM,OP,    SU,SV,SW,ST,SM,SP, 0.5f   );
  stage(SU,SV,SW,ST,SM,SP,    OU,OV,OW,OT,OM,OP, 1.f    );
}

// Round 11
// 365.449 us; speedup vs baseline: 1.9952x; 1.0250x over previous
//
#include <hip/hip_runtime.h>
#include <math.h>

#define NZ 40
#define NY 256
#define NX 256
#define NUX 257                 // Nx+1
#define NYX (NY*NX)             // 65536
#define KU (NY*NUX)             // per-k stride of U
#define KV ((NY+1)*NX)          // per-k stride of V
#define NUT (NZ*KU)
#define NVT (NZ*KV)
#define NCT (NZ*NYX)
#define NWT ((NZ-1)*NYX)
#define NBLK (NUX*NZ)           // 10280 = 8*1285
#define NHALF (NUT+NVT+NWT+3*NCT+NWT)   // total fp16 diag elements (even)

typedef _Float16 h16;

__device__ __forceinline__ int ICc(int k,int j,int i){ return (k*NY+j)*NX+i; }
__device__ __forceinline__ int IU (int k,int j,int i){ return (k*NY+j)*NUX+i; }
__device__ __forceinline__ int IV (int k,int j,int i){ return (k*(NY+1)+j)*NX+i; }

// fast divide: v_rcp_f32 (trans pipe, ~1e-5 rel err).
__device__ __forceinline__ float fdiv(float a, float b){
  return a * __builtin_amdgcn_rcpf(b);
}
__device__ __forceinline__ float ldh(const h16* __restrict__ a, int idx){
  return (float)a[idx];
}

// ---------------- diagnostics: u,v,w,theta,alpha,p,Omega -> fp16 ----------------
// grid (257, NZ), block 256.  j=blockIdx.x, k=blockIdx.y, i=threadIdx.x
__global__ __launch_bounds__(256) void diag_all(
    const float* __restrict__ Us, const float* __restrict__ Vs, const float* __restrict__ Ws,
    const float* __restrict__ Ts, const float* __restrict__ Ms, const float* __restrict__ Ps,
    h16* __restrict__ ud, h16* __restrict__ vd, h16* __restrict__ wd,
    h16* __restrict__ thd, h16* __restrict__ ald, h16* __restrict__ pd,
    h16* __restrict__ Omd,
    const float* __restrict__ dzp, const float* __restrict__ PREFp,
    const float* __restrict__ Rdp, const float* __restrict__ gp)
{
  const int i = threadIdx.x;     // 0..255
  const int j = blockIdx.x;      // 0..256
  const int k = blockIdx.y;
  const float rdz = 1.f/(*dzp);
  const float PREF = *PREFp, Rd = *Rdp, g = *gp;
  const float invP = 1.f/PREF;

  const int jj  = j & 255;
  const int jm1 = (j+255) & 255;

  // v = V / bar_y(pad_y(Mu)) : all j in 0..256
  {
    float mjm = Ms[(k*NY+jm1)*NX+i];
    float mjj = Ms[(k*NY+jj )*NX+i];
    const int o = IV(k,j,i);
    vd[o] = (h16)fdiv(Vs[o], 0.5f*(mjm+mjj));
  }

  if (j < NY) {
    const int b = (k*NY+j)*NX;
    float mi  = Ms[b+i];
    float mim = Ms[b+((i+255)&255)];
    ud[IU(k,j,i)] = (h16)fdiv(Us[IU(k,j,i)], 0.5f*(mim+mi));
    if (i == 255) {   // u edge column i=256
      ud[IU(k,j,256)] = (h16)fdiv(Us[IU(k,j,256)], 0.5f*(Ms[b+255]+Ms[b+0]));
    }

    const int c = b + i;
    float mu   = mi;
    float phim = (k>0)    ? Ps[c-NYX] : 0.f;
    float phik = (k<NZ-1) ? Ps[c]     : 0.f;
    float al   = -((phik-phim)*rdz)*__builtin_amdgcn_rcpf(mu);
    float th   = fdiv(Ts[c], mu);
    // x > 0 by construction: p = PREF * x^1.4 via exp2/log2 (trans pipe)
    float x    = Rd*th*invP*__builtin_amdgcn_rcpf(al);
    pd[c]  = (h16)(PREF*__builtin_amdgcn_exp2f(1.4f*__builtin_amdgcn_logf(x)));
    ald[c] = (h16)al;
    thd[c] = (h16)th;
    if (k < NZ-1) {
      float mup  = Ms[c+NYX];
      float phip = (k+1<NZ-1) ? Ps[c+NYX] : 0.f;
      float alp  = -((phip-phik)*rdz)*__builtin_amdgcn_rcpf(mup);
      float muz  = 0.5f*(mu+mup);
      wd[c]  = (h16)fdiv(Ws[c], muz);
      Omd[c] = (h16)(-Ws[c]*g*__builtin_amdgcn_rcpf(muz*(0.5f*(al+alp))));
    }
  }
}

// ---------------- fused RHS + stage update ----------------
// 1D grid NBLK with XCD swizzle; block 320 (5 waves): threads 0..255 full work,
// thread 256 computes the U edge column in its own wave, 257..319 idle.
__global__ __launch_bounds__(320,8) void rhs_update(
    const float* __restrict__ Us, const float* __restrict__ Vs,
    const float* __restrict__ Ms, const float* __restrict__ Ps,
    const h16* __restrict__ ud, const h16* __restrict__ vd, const h16* __restrict__ wd,
    const h16* __restrict__ thd, const h16* __restrict__ ald, const h16* __restrict__ pd,
    const h16* __restrict__ Omd,
    const float* __restrict__ Ub, const float* __restrict__ Vb, const float* __restrict__ Wb,
    const float* __restrict__ Tb, const float* __restrict__ Mb, const float* __restrict__ Pb,
    float* __restrict__ Uo, float* __restrict__ Vo, float* __restrict__ Wo,
    float* __restrict__ To, float* __restrict__ Mo, float* __restrict__ Po,
    const float* __restrict__ dxp, const float* __restrict__ dyp, const float* __restrict__ dzp,
    const float* __restrict__ dtp, const float* __restrict__ gp, float cmul)
{
  const int i = threadIdx.x;     // 0..319
  if (i > 256) return;

  // bijective XCD swizzle: NBLK = 8 * 1285
  const int bid = blockIdx.x;
  const int nb  = (bid & 7)*(NBLK/8) + (bid >> 3);
  const int j   = nb / NZ;       // 0..256
  const int k   = nb - NZ*j;     // 0..NZ-1

  const float rdx = 1.f/(*dxp), rdy = 1.f/(*dyp), rdz = 1.f/(*dzp);
  const float g = *gp;
  const float c = (*dtp)*cmul;

  const int jj  = j & 255;
  const int jm1 = (j+255) & 255;
  const int jp1c= (j+1) & 255;   // (j+1) wrap on 256-grid (used in j<NY context)
  const int im1 = (i+255) & 255;
  const int ip1 = (i+1) & 255;

  // ================= R_U : j<NY, u-grid index i in [0,256] =================
  if (j < NY) {
    const int iu  = i;
    const int iW  = i ? (i-1) : 256;
    const int iE  = (i==256) ? 0 : (i+1);
    const int ii_  = iu & 255;
    const int iim1 = (iu+255) & 255;
    const int bU   = k*KU + j*NUX;

    float ui0 = ldh(ud,bU+iu), uim = ldh(ud,bU+iW), uip = ldh(ud,bU+iE);
    float Uim = Us[bU+iW], Ui0 = Us[bU+iu], Uip = Us[bU+iE];
    float t1 = -(0.25f*(Ui0+Uip)*(ui0+uip) - 0.25f*(Uim+Ui0)*(uim+ui0))*rdx;

    float Vx0 = 0.5f*(Vs[IV(k,j  ,iim1)] + Vs[IV(k,j  ,ii_)]);
    float uy0 = 0.5f*(ldh(ud,IU(k,jm1,iu)) + ui0);
    float Vx1 = 0.5f*(Vs[IV(k,j+1,iim1)] + Vs[IV(k,j+1,ii_)]);
    float uy1 = 0.5f*(ui0 + ldh(ud,IU(k,jp1c,iu)));
    float t2 = -(Vx1*uy1 - Vx0*uy0)*rdy;

    float Omx0 = (k==0)   ? 0.f : 0.5f*(ldh(Omd,ICc(k-1,j,iim1))+ldh(Omd,ICc(k-1,j,ii_)));
    float uz0  = (k==0)   ? 0.5f*ui0 : 0.5f*(ldh(ud,IU(k-1,j,iu))+ui0);
    float Omx1 = (k+1==NZ)? 0.f : 0.5f*(ldh(Omd,ICc(k,j,iim1))+ldh(Omd,ICc(k,j,ii_)));
    float uz1  = (k+1==NZ)? 0.5f*ui0 : 0.5f*(ui0+ldh(ud,IU(k+1,j,iu)));
    float t3 = -(Omx1*uz1 - Omx0*uz0)*rdz;

    float Mux = 0.5f*(Ms[ICc(k,j,iim1)]+Ms[ICc(k,j,ii_)]);
    float alx = 0.5f*(ldh(ald,ICc(k,j,iim1))+ldh(ald,ICc(k,j,ii_)));
    float pt1 = -Mux*alx*(ldh(pd,ICc(k,j,ii_))-ldh(pd,ICc(k,j,iim1)))*rdx;

    auto pzf = [&](int m, int x)->float {
      if (m==0)  return 0.5f*ldh(pd,ICc(0,j,x));
      if (m==NZ) return 0.5f*ldh(pd,ICc(NZ-1,j,x));
      return 0.5f*(ldh(pd,ICc(m-1,j,x))+ldh(pd,ICc(m,j,x)));
    };
    float A = (0.5f*(pzf(k+1,iim1)+pzf(k+1,ii_)) - 0.5f*(pzf(k,iim1)+pzf(k,ii_)))*rdz;
    auto Phzf = [&](int x)->float {
      if (k==0)    return 0.5f*Ps[ICc(0,j,x)];
      if (k==NZ-1) return 0.5f*Ps[ICc(NZ-2,j,x)];
      return 0.5f*(Ps[ICc(k-1,j,x)]+Ps[ICc(k,j,x)]);
    };
    float B = (Phzf(ii_)-Phzf(iim1))*rdx;

    const int o = bU+iu;
    Uo[o] = Ub[o] + c*(t1+t2+t3+pt1 - A*B);
  }

  if (i >= NX) return;   // thread 256 done (edge only)

  // ================= R_V : all j in 0..256, i<NX =================
  {
    const int jN = (j==0)   ? 256 : j-1;   // (j-1) mod 257 on V-grid
    const int jS = (j==256) ? 0   : j+1;
    float vj0 = ldh(vd,IV(k,j,i));
    float vjm = ldh(vd,IV(k,jN,i));
    float vjp = ldh(vd,IV(k,jS,i));
    float Vjm = Vs[IV(k,jN,i)], Vj0 = Vs[IV(k,j,i)], Vjp = Vs[IV(k,jS,i)];
    float t2 = -(0.25f*(Vj0+Vjp)*(vj0+vjp) - 0.25f*(Vjm+Vj0)*(vjm+vj0))*rdy;

    float Uy0 = 0.5f*(Us[IU(k,jm1,i  )] + Us[IU(k,jj,i  )]);
    float vx0 = 0.5f*(ldh(vd,IV(k,j,im1)) + vj0);
    float Uy1 = 0.5f*(Us[IU(k,jm1,i+1)] + Us[IU(k,jj,i+1)]);
    float vx1 = 0.5f*(vj0 + ldh(vd,IV(k,j,ip1)));
    float t1 = -(Uy1*vx1 - Uy0*vx0)*rdx;

    float Omy0 = (k==0)   ? 0.f : 0.5f*(ldh(Omd,ICc(k-1,jm1,i))+ldh(Omd,ICc(k-1,jj,i)));
    float vz0  = (k==0)   ? 0.5f*vj0 : 0.5f*(ldh(vd,IV(k-1,j,i))+vj0);
    float Omy1 = (k+1==NZ)? 0.f : 0.5f*(ldh(Omd,ICc(k,jm1,i))+ldh(Omd,ICc(k,jj,i)));
    float vz1  = (k+1==NZ)? 0.5f*vj0 : 0.5f*(vj0+ldh(vd,IV(k+1,j,i)));
    float t3 = -(Omy1*vz1 - Omy0*vz0)*rdz;

    float Muy = 0.5f*(Ms[ICc(k,jm1,i)]+Ms[ICc(k,jj,i)]);
    float aly = 0.5f*(ldh(ald,ICc(k,jm1,i))+ldh(ald,ICc(k,jj,i)));
    float pt1 = -Muy*aly*(ldh(pd,ICc(k,jj,i))-ldh(pd,ICc(k,jm1,i)))*rdy;

    auto pzfy = [&](int m, int y)->float {
      if (m==0)  return 0.5f*ldh(pd,ICc(0,y,i));
      if (m==NZ) return 0.5f*ldh(pd,ICc(NZ-1,y,i));
      return 0.5f*(ldh(pd,ICc(m-1,y,i))+ldh(pd,ICc(m,y,i)));
    };
    float A = (0.5f*(pzfy(k+1,jm1)+pzfy(k+1,jj)) - 0.5f*(pzfy(k,jm1)+pzfy(k,jj)))*rdz;
    auto Phzfy = [&](int y)->float {
      if (k==0)    return 0.5f*Ps[ICc(0,y,i)];
      if (k==NZ-1) return 0.5f*Ps[ICc(NZ-2,y,i)];
      return 0.5f*(Ps[ICc(k-1,y,i)]+Ps[ICc(k,y,i)]);
    };
    float B = (Phzfy(jj)-Phzfy(jm1))*rdy;
    float pt2 = -A*B;

    const int o = IV(k,j,i);
    Vo[o] = Vb[o] + c*(t1+t2+t3+pt1+pt2);
  }

  // ================= center fields : j<NY, i<NX =================
  if (j < NY) {
    const int cc = ICc(k,j,i);

    // ---- R_Theta ----
    float th0 = ldh(thd,cc);
    float thx0 = 0.5f*(ldh(thd,ICc(k,j,im1))+th0);
    float thx1 = 0.5f*(th0+ldh(thd,ICc(k,j,ip1)));
    float s1 = -(Us[IU(k,j,i+1)]*thx1 - Us[IU(k,j,i)]*thx0)*rdx;
    float thy0 = 0.5f*(ldh(thd,ICc(k,jm1,i))+th0);
    float thy1 = 0.5f*(th0+ldh(thd,ICc(k,jp1c,i)));
    float s2 = -(Vs[IV(k,j+1,i)]*thy1 - Vs[IV(k,j,i)]*thy0)*rdy;
    float Om0 = (k==0)    ? 0.f : ldh(Omd,ICc(k-1,j,i));
    float Om1 = (k+1==NZ) ? 0.f : ldh(Omd,cc);
    float thz0 = (k==0)    ? 0.5f*th0 : 0.5f*(ldh(thd,ICc(k-1,j,i))+th0);
    float thz1 = (k+1==NZ) ? 0.5f*th0 : 0.5f*(th0+ldh(thd,ICc(k+1,j,i)));
    float s3 = -(Om1*thz1 - Om0*thz0)*rdz;
    To[cc] = Tb[cc] + c*(s1+s2+s3);

    // ---- R_Mu ----
    float rmu = -(Us[IU(k,j,i+1)]-Us[IU(k,j,i)])*rdx
                -(Vs[IV(k,j+1,i)]-Vs[IV(k,j,i)])*rdy
                -(Om1-Om0)*rdz;
    Mo[cc] = Mb[cc] + c*rmu;

    if (k < NZ-1) {
      float w0 = ldh(wd,cc);
      // ---- R_W ----
      float Uz0 = 0.5f*(Us[IU(k,j,i  )]+Us[IU(k+1,j,i  )]);
      float Uz1 = 0.5f*(Us[IU(k,j,i+1)]+Us[IU(k+1,j,i+1)]);
      float wx0 = 0.5f*(ldh(wd,ICc(k,j,im1))+w0);
      float wx1 = 0.5f*(w0+ldh(wd,ICc(k,j,ip1)));
      float q1 = -(Uz1*wx1 - Uz0*wx0)*rdx;
      float Vz0 = 0.5f*(Vs[IV(k,j  ,i)]+Vs[IV(k+1,j  ,i)]);
      float Vz1 = 0.5f*(Vs[IV(k,j+1,i)]+Vs[IV(k+1,j+1,i)]);
      float wy0 = 0.5f*(ldh(wd,ICc(k,jm1,i))+w0);
      float wy1 = 0.5f*(w0+ldh(wd,ICc(k,jp1c,i)));
      float q2 = -(Vz1*wy1 - Vz0*wy0)*rdy;
      float Omz0 = (k==0)      ? 0.5f*ldh(Omd,ICc(0,j,i))    : 0.5f*(ldh(Omd,ICc(k-1,j,i))+ldh(Omd,cc));
      float wz0  = (k==0)      ? 0.5f*w0 : 0.5f*(ldh(wd,ICc(k-1,j,i))+w0);
      float Omz1 = (k+1==NZ-1) ? 0.5f*ldh(Omd,ICc(NZ-2,j,i)) : 0.5f*(ldh(Omd,cc)+ldh(Omd,ICc(k+1,j,i)));
      float wz1  = (k+1==NZ-1) ? 0.5f*w0 : 0.5f*(w0+ldh(wd,ICc(k+1,j,i)));
      float q3 = -(Omz1*wz1 - Omz0*wz0)*rdz;
      float pw = g*((ldh(pd,ICc(k+1,j,i))-ldh(pd,cc))*rdz - 0.5f*(Ms[cc]+Ms[ICc(k+1,j,i)]));
      Wo[cc] = Wb[cc] + c*(q1+q2+q3+pw);

      // ---- R_Phi ----
      float ux0 = 0.5f*(ldh(ud,IU(k  ,j,i))+ldh(ud,IU(k  ,j,i+1)));
      float ux1 = 0.5f*(ldh(ud,IU(k+1,j,i))+ldh(ud,IU(k+1,j,i+1)));
      float uzx = 0.5f*(ux0+ux1);
      float dPhx = 0.5f*(Ps[ICc(k,j,ip1)]-Ps[ICc(k,j,im1)])*rdx;
      float vy0 = 0.5f*(ldh(vd,IV(k  ,j,i))+ldh(vd,IV(k  ,j+1,i)));
      float vy1 = 0.5f*(ldh(vd,IV(k+1,j,i))+ldh(vd,IV(k+1,j+1,i)));
      float vzy = 0.5f*(vy0+vy1);
      float dPhy = 0.5f*(Ps[ICc(k,jp1c,i)]-Ps[ICc(k,jm1,i)])*rdy;
      float Phz0 = (k==0)      ? 0.5f*Ps[ICc(0,j,i)]    : 0.5f*(Ps[ICc(k-1,j,i)]+Ps[cc]);
      float Phz1 = (k+1==NZ-1) ? 0.5f*Ps[ICc(NZ-2,j,i)] : 0.5f*(Ps[cc]+Ps[ICc(k+1,j,i)]);
      float p3 = -ldh(Omd,cc)*(Phz1-Phz0)*rdz;
      Po[cc] = Pb[cc] + c*(-uzx*dPhx - vzy*dPhy + p3 + g*w0);
    }
  }
}

extern "C" void kernel_launch(void* const* d_in, const int* in_sizes, int n_in,
                              void* d_out, int out_size, void* d_ws, size_t ws_size,
                              hipStream_t stream)
{
  const float* U = (const float*)d_in[0];
  const float* V = (const float*)d_in[1];
  const float* W = (const float*)d_in[2];
  const float* T = (const float*)d_in[3];
  const float* M = (const float*)d_in[4];
  const float* P = (const float*)d_in[5];
  const float* dxp  = (const float*)d_in[12];
  const float* dyp  = (const float*)d_in[13];
  const float* dzp  = (const float*)d_in[14];
  const float* dtp  = (const float*)d_in[15];
  const float* PREFp= (const float*)d_in[16];
  const float* Rdp  = (const float*)d_in[17];
  const float* gp   = (const float*)d_in[18];

  h16* hw = (h16*)d_ws;
  h16* ud  = hw;         h16* vd  = ud +NUT;  h16* wd = vd +NVT;
  h16* thd = wd +NWT;    h16* ald = thd+NCT;  h16* pd = ald+NCT;
  h16* Omd = pd +NCT;
  float* S = (float*)(hw + NHALF);   // NHALF even -> 4B aligned
  float* SU=S; float* SV=SU+NUT; float* SW=SV+NVT; float* ST=SW+NWT; float* SM=ST+NCT; float* SP=SM+NCT;

  float* o = (float*)d_out;
  float* OU=o; float* OV=OU+NUT; float* OW=OV+NVT; float* OT=OW+NWT; float* OM=OT+NCT; float* OP=OM+NCT;

  dim3 dblk(256,1,1), dgrd(NUX, NZ, 1);
  dim3 rblk(320,1,1), rgrd(NBLK, 1, 1);

  auto stage = [&](const float* sU,const float* sV,const float* sW,
                   const float* sT,const float* sM,const float* sP,
                   float* oU,float* oV,float* oW,float* oT,float* oM,float* oP,
                   float cmul){
    hipLaunchKernelGGL(diag_all, dgrd, dblk, 0, stream,
                       sU,sV,sW,sT,sM,sP, ud,vd,wd,thd,ald,pd,Omd, dzp,PREFp,Rdp,gp);
    hipLaunchKernelGGL(rhs_update, rgrd, rblk, 0, stream,
                       sU,sV,sM,sP, ud,vd,wd,thd,ald,pd,Omd,
                       U,V,W,T,M,P, oU,oV,oW,oT,oM,oP,
                       dxp,dyp,dzp,dtp,gp, cmul);
  };

  stage(U,V,W,T,M,P,          OU,OV,OW,OT,OM,OP, 1.f/3.f);
  stage(OU,OV,OW,OT,OM,OP,    SU,SV,SW,ST,SM,SP, 0.5f   );
  stage(SU,SV,SW,ST,SM,SP,    OU,OV,OW,OT,OM,OP, 1.f    );
}

// Round 12
// 311.264 us; speedup vs baseline: 2.3425x; 1.1741x over previous
//
#include <hip/hip_runtime.h>
#include <math.h>

#define NZ 40
#define NY 256
#define NX 256
#define NUX 257                 // Nx+1
#define NYX (NY*NX)             // 65536
#define KU (NY*NUX)             // per-k stride of U
#define KV ((NY+1)*NX)          // per-k stride of V
#define NUT (NZ*KU)
#define NVT (NZ*KV)
#define NCT (NZ*NYX)
#define NWT ((NZ-1)*NYX)
#define NBLK (NUX*NZ)           // 10280 = 8*1285
#define NHALF (NUT+NVT+NWT+3*NCT+NWT)   // total fp16 diag elements (even)

typedef _Float16 h16;

__device__ __forceinline__ int ICc(int k,int j,int i){ return (k*NY+j)*NX+i; }
__device__ __forceinline__ int IU (int k,int j,int i){ return (k*NY+j)*NUX+i; }
__device__ __forceinline__ int IV (int k,int j,int i){ return (k*(NY+1)+j)*NX+i; }

// fast divide: v_rcp_f32 (trans pipe, ~1e-5 rel err).
__device__ __forceinline__ float fdiv(float a, float b){
  return a * __builtin_amdgcn_rcpf(b);
}
__device__ __forceinline__ float ldh(const h16* __restrict__ a, int idx){
  return (float)a[idx];
}

// ---------------- diagnostics: u,v,w,theta,alpha,p,Omega -> fp16 ----------------
// grid (257, NZ), block 256.  j=blockIdx.x, k=blockIdx.y, i=threadIdx.x
__global__ __launch_bounds__(256) void diag_all(
    const float* __restrict__ Us, const float* __restrict__ Vs, const float* __restrict__ Ws,
    const float* __restrict__ Ts, const float* __restrict__ Ms, const float* __restrict__ Ps,
    h16* __restrict__ ud, h16* __restrict__ vd, h16* __restrict__ wd,
    h16* __restrict__ thd, h16* __restrict__ ald, h16* __restrict__ pd,
    h16* __restrict__ Omd,
    const float* __restrict__ dzp, const float* __restrict__ PREFp,
    const float* __restrict__ Rdp, const float* __restrict__ gp)
{
  const int i = threadIdx.x;     // 0..255
  const int j = blockIdx.x;      // 0..256
  const int k = blockIdx.y;
  const float rdz = 1.f/(*dzp);
  const float PREF = *PREFp, Rd = *Rdp, g = *gp;
  const float invP = 1.f/PREF;

  const int jj  = j & 255;
  const int jm1 = (j+255) & 255;

  // v = V / bar_y(pad_y(Mu)) : all j in 0..256
  {
    float mjm = Ms[(k*NY+jm1)*NX+i];
    float mjj = Ms[(k*NY+jj )*NX+i];
    const int o = IV(k,j,i);
    vd[o] = (h16)fdiv(Vs[o], 0.5f*(mjm+mjj));
  }

  if (j < NY) {
    const int b = (k*NY+j)*NX;
    float mi  = Ms[b+i];
    float mim = Ms[b+((i+255)&255)];
    ud[IU(k,j,i)] = (h16)fdiv(Us[IU(k,j,i)], 0.5f*(mim+mi));
    if (i == 255) {   // u edge column i=256
      ud[IU(k,j,256)] = (h16)fdiv(Us[IU(k,j,256)], 0.5f*(Ms[b+255]+Ms[b+0]));
    }

    const int c = b + i;
    float mu   = mi;
    float phim = (k>0)    ? Ps[c-NYX] : 0.f;
    float phik = (k<NZ-1) ? Ps[c]     : 0.f;
    float al   = -((phik-phim)*rdz)*__builtin_amdgcn_rcpf(mu);
    float th   = fdiv(Ts[c], mu);
    // x > 0 by construction: p = PREF * x^1.4 via exp2/log2 (trans pipe)
    float x    = Rd*th*invP*__builtin_amdgcn_rcpf(al);
    pd[c]  = (h16)(PREF*__builtin_amdgcn_exp2f(1.4f*__builtin_amdgcn_logf(x)));
    ald[c] = (h16)al;
    thd[c] = (h16)th;
    if (k < NZ-1) {
      float mup  = Ms[c+NYX];
      float phip = (k+1<NZ-1) ? Ps[c+NYX] : 0.f;
      float alp  = -((phip-phik)*rdz)*__builtin_amdgcn_rcpf(mup);
      float muz  = 0.5f*(mu+mup);
      wd[c]  = (h16)fdiv(Ws[c], muz);
      Omd[c] = (h16)(-Ws[c]*g*__builtin_amdgcn_rcpf(muz*(0.5f*(al+alp))));
    }
  }
}

// ---------------- fused RHS + stage update ----------------
// 1D grid NBLK with XCD swizzle; block 256.  out = base + c*R(state)
// (round-7 structure: lane 255 additionally computes the u-grid edge column)
__global__ __launch_bounds__(256,8) void rhs_update(
    const float* __restrict__ Us, const float* __restrict__ Vs,
    const float* __restrict__ Ms, const float* __restrict__ Ps,
    const h16* __restrict__ ud, const h16* __restrict__ vd, const h16* __restrict__ wd,
    const h16* __restrict__ thd, const h16* __restrict__ ald, const h16* __restrict__ pd,
    const h16* __restrict__ Omd,
    const float* __restrict__ Ub, const float* __restrict__ Vb, const float* __restrict__ Wb,
    const float* __restrict__ Tb, const float* __restrict__ Mb, const float* __restrict__ Pb,
    float* __restrict__ Uo, float* __restrict__ Vo, float* __restrict__ Wo,
    float* __restrict__ To, float* __restrict__ Mo, float* __restrict__ Po,
    const float* __restrict__ dxp, const float* __restrict__ dyp, const float* __restrict__ dzp,
    const float* __restrict__ dtp, const float* __restrict__ gp, float cmul)
{
  // bijective XCD swizzle: NBLK = 8 * 1285
  const int bid = blockIdx.x;
  const int nb  = (bid & 7)*(NBLK/8) + (bid >> 3);
  const int j   = nb / NZ;       // 0..256
  const int k   = nb - NZ*j;     // 0..NZ-1
  const int i   = threadIdx.x;   // 0..255

  const float rdx = 1.f/(*dxp), rdy = 1.f/(*dyp), rdz = 1.f/(*dzp);
  const float g = *gp;
  const float c = (*dtp)*cmul;

  const int jj  = j & 255;
  const int jm1 = (j+255) & 255;
  const int jp1c= (j+1) & 255;   // (j+1) wrap on 256-grid (valid in j<NY context)
  const int im1 = (i+255) & 255;
  const int ip1 = (i+1) & 255;

  // ---- R_U value at u-grid index iu (iW/iE are wrapped u-grid neighbors) ----
  auto ru_val = [&](int iu, int iW, int iE)->float {
    const int ii_  = iu & 255;
    const int iim1 = (iu+255) & 255;
    const int bU   = k*KU + j*NUX;

    float ui0 = ldh(ud,bU+iu), uim = ldh(ud,bU+iW), uip = ldh(ud,bU+iE);
    float Uim = Us[bU+iW], Ui0 = Us[bU+iu], Uip = Us[bU+iE];
    float t1 = -(0.25f*(Ui0+Uip)*(ui0+uip) - 0.25f*(Uim+Ui0)*(uim+ui0))*rdx;

    float Vx0 = 0.5f*(Vs[IV(k,j  ,iim1)] + Vs[IV(k,j  ,ii_)]);
    float uy0 = 0.5f*(ldh(ud,IU(k,jm1,iu)) + ui0);
    float Vx1 = 0.5f*(Vs[IV(k,j+1,iim1)] + Vs[IV(k,j+1,ii_)]);
    float uy1 = 0.5f*(ui0 + ldh(ud,IU(k,jp1c,iu)));
    float t2 = -(Vx1*uy1 - Vx0*uy0)*rdy;

    float Omx0 = (k==0)   ? 0.f : 0.5f*(ldh(Omd,ICc(k-1,j,iim1))+ldh(Omd,ICc(k-1,j,ii_)));
    float uz0  = (k==0)   ? 0.5f*ui0 : 0.5f*(ldh(ud,IU(k-1,j,iu))+ui0);
    float Omx1 = (k+1==NZ)? 0.f : 0.5f*(ldh(Omd,ICc(k,j,iim1))+ldh(Omd,ICc(k,j,ii_)));
    float uz1  = (k+1==NZ)? 0.5f*ui0 : 0.5f*(ui0+ldh(ud,IU(k+1,j,iu)));
    float t3 = -(Omx1*uz1 - Omx0*uz0)*rdz;

    float Mux = 0.5f*(Ms[ICc(k,j,iim1)]+Ms[ICc(k,j,ii_)]);
    float alx = 0.5f*(ldh(ald,ICc(k,j,iim1))+ldh(ald,ICc(k,j,ii_)));
    float pt1 = -Mux*alx*(ldh(pd,ICc(k,j,ii_))-ldh(pd,ICc(k,j,iim1)))*rdx;

    auto pzf = [&](int m, int x)->float {
      if (m==0)  return 0.5f*ldh(pd,ICc(0,j,x));
      if (m==NZ) return 0.5f*ldh(pd,ICc(NZ-1,j,x));
      return 0.5f*(ldh(pd,ICc(m-1,j,x))+ldh(pd,ICc(m,j,x)));
    };
    float A = (0.5f*(pzf(k+1,iim1)+pzf(k+1,ii_)) - 0.5f*(pzf(k,iim1)+pzf(k,ii_)))*rdz;
    auto Phzf = [&](int x)->float {
      if (k==0)    return 0.5f*Ps[ICc(0,j,x)];
      if (k==NZ-1) return 0.5f*Ps[ICc(NZ-2,j,x)];
      return 0.5f*(Ps[ICc(k-1,j,x)]+Ps[ICc(k,j,x)]);
    };
    float B = (Phzf(ii_)-Phzf(iim1))*rdx;
    return t1+t2+t3+pt1 + (-A*B);
  };

  // ================= R_U : j<NY =================
  if (j < NY) {
    const int iW = i ? (i-1) : 256;
    float rU = ru_val(i, iW, i+1);
    const int o = IU(k,j,i);
    Uo[o] = Ub[o] + c*rU;
    if (i == 255) {   // U edge column i=256 (wrap: iW=255, iE=0)
      float rUe = ru_val(256, 255, 0);
      const int oe = IU(k,j,256);
      Uo[oe] = Ub[oe] + c*rUe;
    }
  }

  // ================= R_V : all j in 0..256 =================
  {
    const int jN = (j==0)   ? 256 : j-1;   // (j-1) mod 257 on V-grid
    const int jS = (j==256) ? 0   : j+1;
    float vj0 = ldh(vd,IV(k,j,i));
    float vjm = ldh(vd,IV(k,jN,i));
    float vjp = ldh(vd,IV(k,jS,i));
    float Vjm = Vs[IV(k,jN,i)], Vj0 = Vs[IV(k,j,i)], Vjp = Vs[IV(k,jS,i)];
    float t2 = -(0.25f*(Vj0+Vjp)*(vj0+vjp) - 0.25f*(Vjm+Vj0)*(vjm+vj0))*rdy;

    float Uy0 = 0.5f*(Us[IU(k,jm1,i  )] + Us[IU(k,jj,i  )]);
    float vx0 = 0.5f*(ldh(vd,IV(k,j,im1)) + vj0);
    float Uy1 = 0.5f*(Us[IU(k,jm1,i+1)] + Us[IU(k,jj,i+1)]);
    float vx1 = 0.5f*(vj0 + ldh(vd,IV(k,j,ip1)));
    float t1 = -(Uy1*vx1 - Uy0*vx0)*rdx;

    float Omy0 = (k==0)   ? 0.f : 0.5f*(ldh(Omd,ICc(k-1,jm1,i))+ldh(Omd,ICc(k-1,jj,i)));
    float vz0  = (k==0)   ? 0.5f*vj0 : 0.5f*(ldh(vd,IV(k-1,j,i))+vj0);
    float Omy1 = (k+1==NZ)? 0.f : 0.5f*(ldh(Omd,ICc(k,jm1,i))+ldh(Omd,ICc(k,jj,i)));
    float vz1  = (k+1==NZ)? 0.5f*vj0 : 0.5f*(vj0+ldh(vd,IV(k+1,j,i)));
    float t3 = -(Omy1*vz1 - Omy0*vz0)*rdz;

    float Muy = 0.5f*(Ms[ICc(k,jm1,i)]+Ms[ICc(k,jj,i)]);
    float aly = 0.5f*(ldh(ald,ICc(k,jm1,i))+ldh(ald,ICc(k,jj,i)));
    float pt1 = -Muy*aly*(ldh(pd,ICc(k,jj,i))-ldh(pd,ICc(k,jm1,i)))*rdy;

    auto pzfy = [&](int m, int y)->float {
      if (m==0)  return 0.5f*ldh(pd,ICc(0,y,i));
      if (m==NZ) return 0.5f*ldh(pd,ICc(NZ-1,y,i));
      return 0.5f*(ldh(pd,ICc(m-1,y,i))+ldh(pd,ICc(m,y,i)));
    };
    float A = (0.5f*(pzfy(k+1,jm1)+pzfy(k+1,jj)) - 0.5f*(pzfy(k,jm1)+pzfy(k,jj)))*rdz;
    auto Phzfy = [&](int y)->float {
      if (k==0)    return 0.5f*Ps[ICc(0,y,i)];
      if (k==NZ-1) return 0.5f*Ps[ICc(NZ-2,y,i)];
      return 0.5f*(Ps[ICc(k-1,y,i)]+Ps[ICc(k,y,i)]);
    };
    float B = (Phzfy(jj)-Phzfy(jm1))*rdy;
    float pt2 = -A*B;

    const int o = IV(k,j,i);
    Vo[o] = Vb[o] + c*(t1+t2+t3+pt1+pt2);
  }

  // ================= center fields : j<NY =================
  if (j < NY) {
    const int cc = ICc(k,j,i);

    // ---- R_Theta ----
    float th0 = ldh(thd,cc);
    float thx0 = 0.5f*(ldh(thd,ICc(k,j,im1))+th0);
    float thx1 = 0.5f*(th0+ldh(thd,ICc(k,j,ip1)));
    float s1 = -(Us[IU(k,j,i+1)]*thx1 - Us[IU(k,j,i)]*thx0)*rdx;
    float thy0 = 0.5f*(ldh(thd,ICc(k,jm1,i))+th0);
    float thy1 = 0.5f*(th0+ldh(thd,ICc(k,jp1c,i)));
    float s2 = -(Vs[IV(k,j+1,i)]*thy1 - Vs[IV(k,j,i)]*thy0)*rdy;
    float Om0 = (k==0)    ? 0.f : ldh(Omd,ICc(k-1,j,i));
    float Om1 = (k+1==NZ) ? 0.f : ldh(Omd,cc);
    float thz0 = (k==0)    ? 0.5f*th0 : 0.5f*(ldh(thd,ICc(k-1,j,i))+th0);
    float thz1 = (k+1==NZ) ? 0.5f*th0 : 0.5f*(th0+ldh(thd,ICc(k+1,j,i)));
    float s3 = -(Om1*thz1 - Om0*thz0)*rdz;
    To[cc] = Tb[cc] + c*(s1+s2+s3);

    // ---- R_Mu ----
    float rmu = -(Us[IU(k,j,i+1)]-Us[IU(k,j,i)])*rdx
                -(Vs[IV(k,j+1,i)]-Vs[IV(k,j,i)])*rdy
                -(Om1-Om0)*rdz;
    Mo[cc] = Mb[cc] + c*rmu;

    if (k < NZ-1) {
      float w0 = ldh(wd,cc);
      // ---- R_W ----
      float Uz0 = 0.5f*(Us[IU(k,j,i  )]+Us[IU(k+1,j,i  )]);
      float Uz1 = 0.5f*(Us[IU(k,j,i+1)]+Us[IU(k+1,j,i+1)]);
      float wx0 = 0.5f*(ldh(wd,ICc(k,j,im1))+w0);
      float wx1 = 0.5f*(w0+ldh(wd,ICc(k,j,ip1)));
      float q1 = -(Uz1*wx1 - Uz0*wx0)*rdx;
      float Vz0 = 0.5f*(Vs[IV(k,j  ,i)]+Vs[IV(k+1,j  ,i)]);
      float Vz1 = 0.5f*(Vs[IV(k,j+1,i)]+Vs[IV(k+1,j+1,i)]);
      float wy0 = 0.5f*(ldh(wd,ICc(k,jm1,i))+w0);
      float wy1 = 0.5f*(w0+ldh(wd,ICc(k,jp1c,i)));
      float q2 = -(Vz1*wy1 - Vz0*wy0)*rdy;
      float Omz0 = (k==0)      ? 0.5f*ldh(Omd,ICc(0,j,i))    : 0.5f*(ldh(Omd,ICc(k-1,j,i))+ldh(Omd,cc));
      float wz0  = (k==0)      ? 0.5f*w0 : 0.5f*(ldh(wd,ICc(k-1,j,i))+w0);
      float Omz1 = (k+1==NZ-1) ? 0.5f*ldh(Omd,ICc(NZ-2,j,i)) : 0.5f*(ldh(Omd,cc)+ldh(Omd,ICc(k+1,j,i)));
      float wz1  = (k+1==NZ-1) ? 0.5f*w0 : 0.5f*(w0+ldh(wd,ICc(k+1,j,i)));
      float q3 = -(Omz1*wz1 - Omz0*wz0)*rdz;
      float pw = g*((ldh(pd,ICc(k+1,j,i))-ldh(pd,cc))*rdz - 0.5f*(Ms[cc]+Ms[ICc(k+1,j,i)]));
      Wo[cc] = Wb[cc] + c*(q1+q2+q3+pw);

      // ---- R_Phi ----
      float ux0 = 0.5f*(ldh(ud,IU(k  ,j,i))+ldh(ud,IU(k  ,j,i+1)));
      float ux1 = 0.5f*(ldh(ud,IU(k+1,j,i))+ldh(ud,IU(k+1,j,i+1)));
      float uzx = 0.5f*(ux0+ux1);
      float dPhx = 0.5f*(Ps[ICc(k,j,ip1)]-Ps[ICc(k,j,im1)])*rdx;
      float vy0 = 0.5f*(ldh(vd,IV(k  ,j,i))+ldh(vd,IV(k  ,j+1,i)));
      float vy1 = 0.5f*(ldh(vd,IV(k+1,j,i))+ldh(vd,IV(k+1,j+1,i)));
      float vzy = 0.5f*(vy0+vy1);
      float dPhy = 0.5f*(Ps[ICc(k,jp1c,i)]-Ps[ICc(k,jm1,i)])*rdy;
      float Phz0 = (k==0)      ? 0.5f*Ps[ICc(0,j,i)]    : 0.5f*(Ps[ICc(k-1,j,i)]+Ps[cc]);
      float Phz1 = (k+1==NZ-1) ? 0.5f*Ps[ICc(NZ-2,j,i)] : 0.5f*(Ps[cc]+Ps[ICc(k+1,j,i)]);
      float p3 = -ldh(Omd,cc)*(Phz1-Phz0)*rdz;
      Po[cc] = Pb[cc] + c*(-uzx*dPhx - vzy*dPhy + p3 + g*w0);
    }
  }
}

extern "C" void kernel_launch(void* const* d_in, const int* in_sizes, int n_in,
                              void* d_out, int out_size, void* d_ws, size_t ws_size,
                              hipStream_t stream)
{
  const float* U = (const float*)d_in[0];
  const float* V = (const float*)d_in[1];
  const float* W = (const float*)d_in[2];
  const float* T = (const float*)d_in[3];
  const float* M = (const float*)d_in[4];
  const float* P = (const float*)d_in[5];
  const float* dxp  = (const float*)d_in[12];
  const float* dyp  = (const float*)d_in[13];
  const float* dzp  = (const float*)d_in[14];
  const float* dtp  = (const float*)d_in[15];
  const float* PREFp= (const float*)d_in[16];
  const float* Rdp  = (const float*)d_in[17];
  const float* gp   = (const float*)d_in[18];

  h16* hw = (h16*)d_ws;
  h16* ud  = hw;         h16* vd  = ud +NUT;  h16* wd = vd +NVT;
  h16* thd = wd +NWT;    h16* ald = thd+NCT;  h16* pd = ald+NCT;
  h16* Omd = pd +NCT;
  float* S = (float*)(hw + NHALF);   // NHALF even -> 4B aligned
  float* SU=S; float* SV=SU+NUT; float* SW=SV+NVT; float* ST=SW+NWT; float* SM=ST+NCT; float* SP=SM+NCT;

  float* o = (float*)d_out;
  float* OU=o; float* OV=OU+NUT; float* OW=OV+NVT; float* OT=OW+NWT; float* OM=OT+NCT; float* OP=OM+NCT;

  dim3 dblk(256,1,1), dgrd(NUX, NZ, 1);
  dim3 rblk(256,1,1), rgrd(NBLK, 1, 1);

  auto stage = [&](const float* sU,const float* sV,const float* sW,
                   const float* sT,const float* sM,const float* sP,
                   float* oU,float* oV,float* oW,float* oT,float* oM,float* oP,
                   float cmul){
    hipLaunchKernelGGL(diag_all, dgrd, dblk, 0, stream,
                       sU,sV,sW,sT,sM,sP, ud,vd,wd,thd,ald,pd,Omd, dzp,PREFp,Rdp,gp);
    hipLaunchKernelGGL(rhs_update, rgrd, rblk, 0, stream,
                       sU,sV,sM,sP, ud,vd,wd,thd,ald,pd,Omd,
                       U,V,W,T,M,P, oU,oV,oW,oT,oM,oP,
                       dxp,dyp,dzp,dtp,gp, cmul);
  };

  stage(U,V,W,T,M,P,          OU,OV,OW,OT,OM,OP, 1.f/3.f);
  stage(OU,OV,OW,OT,OM,OP,    SU,SV,SW,ST,SM,SP, 0.5f   );
  stage(SU,SV,SW,ST,SM,SP,    OU,OV,OW,OT,OM,OP, 1.f    );
}